// Round 1
// 280.179 us; speedup vs baseline: 1.0001x; 1.0001x over previous
//
#include <hip/hip_runtime.h>
#include <stdint.h>

// B=131072 rows, K=IN=256, N=OUT=256.
// temp = act @ weight.T (exact int32, |t| < 2^23); r = max|temp|;
// bw = ceil(log2(max(r,1))) (0 if r<=1); shift = bw-7;
// shift>0 ? round_shift(temp,shift) clipped to [-127,127] : int8-wrap(temp)
// exp_out = exp_in + weight_exp + max(shift,0)  (int16 semantics)
// Harness reads d_out as INT32: [B*N values, 1 exp scalar].
//
// Strategy (v2): GEMM ONCE. k1 = GEMM -> store RAW int32 acc into d_out
// + global abs-max reduction. k2 = in-place elementwise quantize of d_out
// (raw temp is LLC-resident: 134 MB < 256 MB Infinity Cache).
// This removes the entire second GEMM (act re-read + bf16 repack + LDS
// staging + MFMA) that the previous version paid for.

#define M_ROWS 131072
#define NK 256
#define BM 64
#define BK 64
#define BKP 72      // padded LDS row stride (bf16 elems) = 144 B

typedef __attribute__((ext_vector_type(8))) short bf16x8;
typedef __attribute__((ext_vector_type(4))) float f32x4;
typedef __attribute__((ext_vector_type(4))) float fv4;
typedef __attribute__((ext_vector_type(4))) int iv4;
typedef __attribute__((ext_vector_type(4))) unsigned int u32x4;
typedef __attribute__((ext_vector_type(4))) unsigned short us4;

__device__ __forceinline__ uint32_t pack_bf16(float a, float b) {
  // exact for integer-valued floats |v| <= 255
  return (__float_as_uint(a) >> 16) | (__float_as_uint(b) & 0xFFFF0000u);
}

// Prepass: weight fp32 -> bf16 (65536 elems; stays L2/LLC-resident, 128 KB).
// Also zero-inits gmax (replaces the separate hipMemsetAsync dispatch).
__global__ void wconv(const float* __restrict__ w, unsigned short* __restrict__ wb,
                      int* __restrict__ gmax) {
  if (blockIdx.x == 0 && threadIdx.x == 0) *gmax = 0;
  const int i = blockIdx.x * 256 + threadIdx.x;
  const fv4 f = ((const fv4*)w)[i];
  us4 o;
  o.x = (unsigned short)(__float_as_uint(f.x) >> 16);
  o.y = (unsigned short)(__float_as_uint(f.y) >> 16);
  o.z = (unsigned short)(__float_as_uint(f.z) >> 16);
  o.w = (unsigned short)(__float_as_uint(f.w) >> 16);
  ((us4*)wb)[i] = o;
}

// GEMM body: computes acc[4][4] (f32x4) for this block/wave.
// 256 threads (4 waves); block tile 64 x 256 (full N); wave w: cols w*64..+63.
__device__ __forceinline__ void gemm_tile(
    const float* __restrict__ act, const unsigned short* __restrict__ wgtb,
    short* As, short* Bs, f32x4 acc[4][4])
{
  const int tid  = threadIdx.x;
  const int bm   = blockIdx.x * BM;
  const int lane = tid & 63;
  const int wave = tid >> 6;
  const int lm   = lane & 15;
  const int lk   = lane >> 4;
  const int wn   = wave * 64;

  const int arow = tid >> 3, aks = (tid & 7) * 8;   // A: 2 chunks (8 fp32->bf16)
  const int brow = tid >> 3, bks = (tid & 7) * 8;   // B: 8 chunks (8 bf16)

  uint32_t apk[2][4];
  u32x4 breg[8];

#pragma unroll
  for (int j = 0; j < 2; ++j) {
    const float* p = act + (size_t)(bm + arow + j * 32) * NK + aks;
    const fv4 f0 = *(const fv4*)p;
    const fv4 f1 = *((const fv4*)p + 1);
    apk[j][0] = pack_bf16(f0.x, f0.y); apk[j][1] = pack_bf16(f0.z, f0.w);
    apk[j][2] = pack_bf16(f1.x, f1.y); apk[j][3] = pack_bf16(f1.z, f1.w);
  }
#pragma unroll
  for (int j = 0; j < 8; ++j)
    breg[j] = *(const u32x4*)(wgtb + (size_t)(brow + j * 32) * NK + bks);

  for (int kt = 0; kt < NK; kt += BK) {
    __syncthreads();
#pragma unroll
    for (int j = 0; j < 2; ++j)
      *(u32x4*)&As[(arow + j * 32) * BKP + aks] = *(const u32x4*)apk[j];
#pragma unroll
    for (int j = 0; j < 8; ++j)
      *(u32x4*)&Bs[(brow + j * 32) * BKP + bks] = breg[j];
    __syncthreads();

    if (kt + BK < NK) {
      const int ktn = kt + BK;
#pragma unroll
      for (int j = 0; j < 2; ++j) {
        const float* p = act + (size_t)(bm + arow + j * 32) * NK + ktn + aks;
        const fv4 f0 = *(const fv4*)p;
        const fv4 f1 = *((const fv4*)p + 1);
        apk[j][0] = pack_bf16(f0.x, f0.y); apk[j][1] = pack_bf16(f0.z, f0.w);
        apk[j][2] = pack_bf16(f1.x, f1.y); apk[j][3] = pack_bf16(f1.z, f1.w);
      }
#pragma unroll
      for (int j = 0; j < 8; ++j)
        breg[j] = *(const u32x4*)(wgtb + (size_t)(brow + j * 32) * NK + ktn + bks);
    }

#pragma unroll
    for (int kk = 0; kk < BK; kk += 32) {
      bf16x8 af[4], bfr[4];
#pragma unroll
      for (int mi = 0; mi < 4; ++mi)
        af[mi] = *(const bf16x8*)&As[(mi * 16 + lm) * BKP + kk + lk * 8];
#pragma unroll
      for (int ni = 0; ni < 4; ++ni)
        bfr[ni] = *(const bf16x8*)&Bs[(wn + ni * 16 + lm) * BKP + kk + lk * 8];
#pragma unroll
      for (int mi = 0; mi < 4; ++mi)
#pragma unroll
        for (int ni = 0; ni < 4; ++ni)
          acc[mi][ni] = __builtin_amdgcn_mfma_f32_16x16x32_bf16(
              af[mi], bfr[ni], acc[mi][ni], 0, 0, 0);
    }
  }
}

// k1: GEMM -> store RAW int32 accumulators into d_out (cached stores: we
// WANT them LLC-resident for k2's re-read) + global abs-max.
__global__ __launch_bounds__(256, 3) void gemm_maxstore(
    const float* __restrict__ act, const unsigned short* __restrict__ wgtb,
    int* __restrict__ out, int* __restrict__ gmax)
{
  __shared__ __align__(16) short As[BM * BKP];
  __shared__ __align__(16) short Bs[NK * BKP];
  __shared__ int smax;
  const int tid = threadIdx.x;
  if (tid == 0) smax = 0;

  f32x4 acc[4][4] = {};
  gemm_tile(act, wgtb, As, Bs, acc);

  const int bm   = blockIdx.x * BM;
  const int lane = tid & 63;
  const int lm   = lane & 15;
  const int lk   = lane >> 4;
  const int wn   = (tid >> 6) * 64;

  int imax = 0;
#pragma unroll
  for (int mi = 0; mi < 4; ++mi)
#pragma unroll
    for (int ni = 0; ni < 4; ++ni)
#pragma unroll
      for (int r = 0; r < 4; ++r) {
        const int ti = (int)acc[mi][ni][r];
        const int a = ti < 0 ? -ti : ti;
        imax = a > imax ? a : imax;
        const int m = bm + mi * 16 + lk * 4 + r;
        const int n = wn + ni * 16 + lm;
        out[(size_t)m * NK + n] = ti;   // raw temp, cached (LLC) store
      }
#pragma unroll
  for (int off = 32; off; off >>= 1) {
    const int o = __shfl_xor(imax, off, 64);
    imax = o > imax ? o : imax;
  }
  if ((tid & 63) == 0) atomicMax(&smax, imax);
  __syncthreads();
  if (tid == 0) atomicMax(gmax, smax);
}

// k2: in-place elementwise quantize of d_out (raw temp is LLC-hot).
__global__ __launch_bounds__(256) void quant_pass(
    int* __restrict__ out, const int* __restrict__ gmax,
    const int* __restrict__ exp_in, const int* __restrict__ wexp)
{
  const int rmax = *gmax;
  const int bw = (rmax <= 1) ? 0 : (32 - __clz(rmax - 1));   // ceil(log2(r))
  const int shift = bw - 7;
  const bool pos = shift > 0;
  const int s = shift < 1 ? 1 : shift;

  const size_t total  = (size_t)M_ROWS * NK / 4;  // int4 vectors
  const size_t stride = (size_t)gridDim.x * blockDim.x;
  for (size_t i = (size_t)blockIdx.x * blockDim.x + threadIdx.x; i < total;
       i += stride) {
    iv4 t = ((const iv4*)out)[i];
    iv4 q;
#pragma unroll
    for (int j = 0; j < 4; ++j) {
      const int ti = t[j];
      int r;
      if (pos) {
        const int rt = ti >> s;                       // floor(t / 2^s)
        const int dec = (ti - (rt << s)) >> (s - 1);  // {0,1}
        r = rt + dec;
        r = r > 127 ? 127 : (r < -127 ? -127 : r);
      } else {
        r = (int)(signed char)(ti & 0xFF);            // int8 wrap
      }
      q[j] = r;
    }
    __builtin_nontemporal_store(q, &((iv4*)out)[i]); // final, never re-read
  }

  if (blockIdx.x == 0 && threadIdx.x == 0) {
    const int e = exp_in[0] + wexp[0] + (pos ? shift : 0);
    out[(size_t)M_ROWS * NK] = (int)(short)e;
  }
}

extern "C" void kernel_launch(void* const* d_in, const int* in_sizes, int n_in,
                              void* d_out, int out_size, void* d_ws, size_t ws_size,
                              hipStream_t stream) {
  const float* act   = (const float*)d_in[0];
  const int* exp_in  = (const int*)d_in[1];
  const float* wgt   = (const float*)d_in[2];
  const int* wexp    = (const int*)d_in[3];
  int* gmax          = (int*)d_ws;
  unsigned short* wb = (unsigned short*)((char*)d_ws + 128);  // 128 KB bf16 weight

  wconv<<<dim3(64), dim3(256), 0, stream>>>(wgt, wb, gmax);
  gemm_maxstore<<<dim3(M_ROWS / BM), dim3(256), 0, stream>>>(act, wb, (int*)d_out,
                                                             gmax);
  quant_pass<<<dim3(2048), dim3(256), 0, stream>>>((int*)d_out, gmax, exp_in, wexp);
}